// Round 1
// baseline (3539.899 us; speedup 1.0000x reference)
//
#include <hip/hip_runtime.h>
#include <hip/hip_bf16.h>

// LightGCN: x = concat(user_emb, item_emb); 3x [x = segsum(val * x[src] by dst)],
// acc = sum of all 4 x's; out = (acc/4)[u rows].
// Strategy: build CSR-by-dst on device each call (histogram+scan+scatter),
// then atomic-free SpMV: one wave per node, lane = feature dim (d=64).

constexpr int SCAN_BS = 256;

__global__ void concat_kernel(const float4* __restrict__ ue, const float4* __restrict__ ie,
                              float4* __restrict__ x, long n_user4, long total4) {
    long i = (long)blockIdx.x * blockDim.x + threadIdx.x;
    long stride = (long)gridDim.x * blockDim.x;
    for (; i < total4; i += stride)
        x[i] = (i < n_user4) ? ue[i] : ie[i - n_user4];
}

__global__ void hist_kernel(const int* __restrict__ dst, int* counts, int n) {
    int i = blockIdx.x * blockDim.x + threadIdx.x;
    int stride = gridDim.x * blockDim.x;
    for (; i < n; i += stride) atomicAdd(&counts[dst[i]], 1);
}

// Per-block exclusive scan (Hillis-Steele in LDS) + per-block totals.
__global__ void scan_blocks_kernel(const int* __restrict__ counts, int* __restrict__ row_ptr,
                                   int* __restrict__ blk_sums, int n) {
    __shared__ int tmp[SCAN_BS];
    int tid = threadIdx.x;
    int i = blockIdx.x * SCAN_BS + tid;
    int v = (i < n) ? counts[i] : 0;
    tmp[tid] = v;
    __syncthreads();
    for (int off = 1; off < SCAN_BS; off <<= 1) {
        int t = (tid >= off) ? tmp[tid - off] : 0;
        __syncthreads();
        tmp[tid] += t;
        __syncthreads();
    }
    if (i < n) row_ptr[i] = tmp[tid] - v;          // exclusive
    if (tid == SCAN_BS - 1) blk_sums[blockIdx.x] = tmp[tid];
}

// Single-block exclusive scan of block sums (nblk <= 1024).
__global__ void scan_sums_kernel(int* blk_sums, int nblk) {
    __shared__ int tmp[1024];
    int tid = threadIdx.x;
    int v = (tid < nblk) ? blk_sums[tid] : 0;
    tmp[tid] = v;
    __syncthreads();
    for (int off = 1; off < 1024; off <<= 1) {
        int t = (tid >= off) ? tmp[tid - off] : 0;
        __syncthreads();
        tmp[tid] += t;
        __syncthreads();
    }
    if (tid < nblk) blk_sums[tid] = tmp[tid] - v;  // exclusive
}

__global__ void scan_finalize_kernel(int* __restrict__ row_ptr, const int* __restrict__ blk_sums,
                                     int* __restrict__ cursor, int n, int n_edges) {
    int i = blockIdx.x * SCAN_BS + threadIdx.x;
    if (i < n) {
        int r = row_ptr[i] + blk_sums[blockIdx.x];
        row_ptr[i] = r;
        cursor[i] = r;
    }
    if (i == 0) row_ptr[n] = n_edges;
}

__global__ void scatter_kernel(const int* __restrict__ src, const int* __restrict__ dst,
                               const float* __restrict__ val, int* cursor,
                               int* __restrict__ csr_src, float* __restrict__ csr_val, int n) {
    int i = blockIdx.x * blockDim.x + threadIdx.x;
    int stride = gridDim.x * blockDim.x;
    for (; i < n; i += stride) {
        int d = dst[i];
        int p = atomicAdd(&cursor[d], 1);
        csr_src[p] = src[i];
        csr_val[p] = val[i];
    }
}

// One wave per node; lane = feature dim. Atomic-free, register accumulation.
__global__ __launch_bounds__(256) void spmv_kernel(
        const float* __restrict__ x, float* __restrict__ y,
        const int* __restrict__ row_ptr, const int* __restrict__ csr_src,
        const float* __restrict__ csr_val, int n_nodes) {
    int lane = threadIdx.x & 63;
    int node = blockIdx.x * 4 + (threadIdx.x >> 6);
    if (node >= n_nodes) return;
    int e0 = row_ptr[node];
    int e1 = row_ptr[node + 1];
    float acc = 0.f;
    for (int e = e0; e < e1; ++e) {
        int s = csr_src[e];
        float v = csr_val[e];
        acc = fmaf(v, x[(size_t)s * 64 + lane], acc);
    }
    y[(size_t)node * 64 + lane] = acc;
}

__global__ void out_accum_kernel(const float* __restrict__ x, const int* __restrict__ u,
                                 float* __restrict__ out, int first) {
    int i = blockIdx.x;
    int lane = threadIdx.x;
    float v = 0.25f * x[(size_t)u[i] * 64 + lane];
    if (first) out[(size_t)i * 64 + lane] = v;
    else       out[(size_t)i * 64 + lane] += v;
}

// Fallback if workspace is too small for CSR: edge-parallel atomic scatter.
__global__ void spmv_atomic_kernel(const float* __restrict__ x, float* y,
                                   const int* __restrict__ src, const int* __restrict__ dst,
                                   const float* __restrict__ val, int n_edges) {
    int lane = threadIdx.x & 63;
    int e = blockIdx.x * (blockDim.x >> 6) + (threadIdx.x >> 6);
    if (e >= n_edges) return;
    float v = val[e];
    atomicAdd(&y[(size_t)dst[e] * 64 + lane], v * x[(size_t)src[e] * 64 + lane]);
}

extern "C" void kernel_launch(void* const* d_in, const int* in_sizes, int n_in,
                              void* d_out, int out_size, void* d_ws, size_t ws_size,
                              hipStream_t stream) {
    const float* user_emb = (const float*)d_in[0];
    const float* item_emb = (const float*)d_in[1];
    const int*   edge_src = (const int*)d_in[2];
    const int*   edge_dst = (const int*)d_in[3];
    const float* edge_val = (const float*)d_in[4];
    const int*   u        = (const int*)d_in[5];
    float* out = (float*)d_out;

    const int n_users = in_sizes[0] / 64;
    const int n_items = in_sizes[1] / 64;
    const int n_nodes = n_users + n_items;
    const int n_edges = in_sizes[2];
    const int n_u     = in_sizes[5];

    const size_t xbytes = (size_t)n_nodes * 64 * sizeof(float);
    char* w = (char*)d_ws;
    float* x_a = (float*)w; w += xbytes;
    float* x_b = (float*)w; w += xbytes;

    // concat -> x_a
    long n_user4 = (long)n_users * 16;
    long total4  = (long)n_nodes * 16;
    concat_kernel<<<2048, 256, 0, stream>>>((const float4*)user_emb, (const float4*)item_emb,
                                            (float4*)x_a, n_user4, total4);

    const size_t csr_need = 2 * xbytes + 2 * (size_t)n_edges * 4
                          + ((size_t)n_nodes + 1) * 4 + (size_t)n_nodes * 4 + 4096;
    const bool use_csr = (ws_size >= csr_need);

    float* cur = x_a;
    float* nxt = x_b;

    out_accum_kernel<<<n_u, 64, 0, stream>>>(cur, u, out, 1);

    if (use_csr) {
        int*   csr_src  = (int*)w;   w += (size_t)n_edges * 4;
        float* csr_val  = (float*)w; w += (size_t)n_edges * 4;
        int*   row_ptr  = (int*)w;   w += ((size_t)n_nodes + 1) * 4;
        int*   cursor   = (int*)w;   w += (size_t)n_nodes * 4;
        int*   blk_sums = (int*)w;

        hipMemsetAsync(cursor, 0, (size_t)n_nodes * 4, stream);
        hist_kernel<<<2048, 256, 0, stream>>>(edge_dst, cursor, n_edges);
        int nblk = (n_nodes + SCAN_BS - 1) / SCAN_BS;   // 586 for this shape (<=1024)
        scan_blocks_kernel<<<nblk, SCAN_BS, 0, stream>>>(cursor, row_ptr, blk_sums, n_nodes);
        scan_sums_kernel<<<1, 1024, 0, stream>>>(blk_sums, nblk);
        scan_finalize_kernel<<<nblk, SCAN_BS, 0, stream>>>(row_ptr, blk_sums, cursor,
                                                           n_nodes, n_edges);
        scatter_kernel<<<2048, 256, 0, stream>>>(edge_src, edge_dst, edge_val, cursor,
                                                 csr_src, csr_val, n_edges);

        for (int l = 0; l < 3; ++l) {
            spmv_kernel<<<(n_nodes + 3) / 4, 256, 0, stream>>>(cur, nxt, row_ptr,
                                                               csr_src, csr_val, n_nodes);
            out_accum_kernel<<<n_u, 64, 0, stream>>>(nxt, u, out, 0);
            float* t = cur; cur = nxt; nxt = t;
        }
    } else {
        for (int l = 0; l < 3; ++l) {
            hipMemsetAsync(nxt, 0, xbytes, stream);
            spmv_atomic_kernel<<<(n_edges + 3) / 4, 256, 0, stream>>>(cur, nxt, edge_src,
                                                                      edge_dst, edge_val, n_edges);
            out_accum_kernel<<<n_u, 64, 0, stream>>>(nxt, u, out, 0);
            float* t = cur; cur = nxt; nxt = t;
        }
    }
}

// Round 2
// 2350.673 us; speedup vs baseline: 1.5059x; 1.5059x over previous
//
#include <hip/hip_runtime.h>
#include <hip/hip_bf16.h>

// LightGCN: x = concat(user_emb, item_emb); 3x [x = segsum(val * x[src] by dst)],
// acc = sum of all 4 x's; out = (acc/4)[u rows].
// R2: interleaved int2 CSR {src, val_bits}; spmv unrolled x8 for 8 gathers in
// flight per wave (R1 was latency-bound: VGPR=8, VALUBusy 17%, serial chain).

constexpr int SCAN_BS = 256;

__global__ void concat_kernel(const float4* __restrict__ ue, const float4* __restrict__ ie,
                              float4* __restrict__ x, long n_user4, long total4) {
    long i = (long)blockIdx.x * blockDim.x + threadIdx.x;
    long stride = (long)gridDim.x * blockDim.x;
    for (; i < total4; i += stride)
        x[i] = (i < n_user4) ? ue[i] : ie[i - n_user4];
}

__global__ void hist_kernel(const int* __restrict__ dst, int* counts, int n) {
    int i = blockIdx.x * blockDim.x + threadIdx.x;
    int stride = gridDim.x * blockDim.x;
    for (; i < n; i += stride) atomicAdd(&counts[dst[i]], 1);
}

// Per-block exclusive scan (Hillis-Steele in LDS) + per-block totals.
__global__ void scan_blocks_kernel(const int* __restrict__ counts, int* __restrict__ row_ptr,
                                   int* __restrict__ blk_sums, int n) {
    __shared__ int tmp[SCAN_BS];
    int tid = threadIdx.x;
    int i = blockIdx.x * SCAN_BS + tid;
    int v = (i < n) ? counts[i] : 0;
    tmp[tid] = v;
    __syncthreads();
    for (int off = 1; off < SCAN_BS; off <<= 1) {
        int t = (tid >= off) ? tmp[tid - off] : 0;
        __syncthreads();
        tmp[tid] += t;
        __syncthreads();
    }
    if (i < n) row_ptr[i] = tmp[tid] - v;          // exclusive
    if (tid == SCAN_BS - 1) blk_sums[blockIdx.x] = tmp[tid];
}

// Single-block exclusive scan of block sums (nblk <= 1024).
__global__ void scan_sums_kernel(int* blk_sums, int nblk) {
    __shared__ int tmp[1024];
    int tid = threadIdx.x;
    int v = (tid < nblk) ? blk_sums[tid] : 0;
    tmp[tid] = v;
    __syncthreads();
    for (int off = 1; off < 1024; off <<= 1) {
        int t = (tid >= off) ? tmp[tid - off] : 0;
        __syncthreads();
        tmp[tid] += t;
        __syncthreads();
    }
    if (tid < nblk) blk_sums[tid] = tmp[tid] - v;  // exclusive
}

__global__ void scan_finalize_kernel(int* __restrict__ row_ptr, const int* __restrict__ blk_sums,
                                     int* __restrict__ cursor, int n, int n_edges) {
    int i = blockIdx.x * SCAN_BS + threadIdx.x;
    if (i < n) {
        int r = row_ptr[i] + blk_sums[blockIdx.x];
        row_ptr[i] = r;
        cursor[i] = r;
    }
    if (i == 0) row_ptr[n] = n_edges;
}

// Scatter into interleaved CSR: one 8B store per edge instead of two 4B.
__global__ void scatter_kernel(const int* __restrict__ src, const int* __restrict__ dst,
                               const float* __restrict__ val, int* cursor,
                               int2* __restrict__ csr, int n) {
    int i = blockIdx.x * blockDim.x + threadIdx.x;
    int stride = gridDim.x * blockDim.x;
    for (; i < n; i += stride) {
        int d = dst[i];
        int p = atomicAdd(&cursor[d], 1);
        csr[p] = make_int2(src[i], __float_as_int(val[i]));
    }
}

// One wave per node; lane = feature dim. Unroll x8: 8 independent gathers in
// flight per wave (the R1 kernel had exactly 1 -> latency-bound at 810us).
__global__ __launch_bounds__(256) void spmv_kernel(
        const float* __restrict__ x, float* __restrict__ y,
        const int* __restrict__ row_ptr, const int2* __restrict__ csr, int n_nodes) {
    int lane = threadIdx.x & 63;
    int node = blockIdx.x * 4 + (threadIdx.x >> 6);
    if (node >= n_nodes) return;
    int e0 = row_ptr[node];
    int e1 = row_ptr[node + 1];
    float a0 = 0.f, a1 = 0.f, a2 = 0.f, a3 = 0.f;
    float a4 = 0.f, a5 = 0.f, a6 = 0.f, a7 = 0.f;
    int e = e0;
    for (; e + 8 <= e1; e += 8) {
        int2 q0 = csr[e + 0];
        int2 q1 = csr[e + 1];
        int2 q2 = csr[e + 2];
        int2 q3 = csr[e + 3];
        int2 q4 = csr[e + 4];
        int2 q5 = csr[e + 5];
        int2 q6 = csr[e + 6];
        int2 q7 = csr[e + 7];
        float g0 = x[(size_t)q0.x * 64 + lane];
        float g1 = x[(size_t)q1.x * 64 + lane];
        float g2 = x[(size_t)q2.x * 64 + lane];
        float g3 = x[(size_t)q3.x * 64 + lane];
        float g4 = x[(size_t)q4.x * 64 + lane];
        float g5 = x[(size_t)q5.x * 64 + lane];
        float g6 = x[(size_t)q6.x * 64 + lane];
        float g7 = x[(size_t)q7.x * 64 + lane];
        a0 = fmaf(__int_as_float(q0.y), g0, a0);
        a1 = fmaf(__int_as_float(q1.y), g1, a1);
        a2 = fmaf(__int_as_float(q2.y), g2, a2);
        a3 = fmaf(__int_as_float(q3.y), g3, a3);
        a4 = fmaf(__int_as_float(q4.y), g4, a4);
        a5 = fmaf(__int_as_float(q5.y), g5, a5);
        a6 = fmaf(__int_as_float(q6.y), g6, a6);
        a7 = fmaf(__int_as_float(q7.y), g7, a7);
    }
    for (; e < e1; ++e) {
        int2 q = csr[e];
        a0 = fmaf(__int_as_float(q.y), x[(size_t)q.x * 64 + lane], a0);
    }
    y[(size_t)node * 64 + lane] = ((a0 + a1) + (a2 + a3)) + ((a4 + a5) + (a6 + a7));
}

__global__ void out_accum_kernel(const float* __restrict__ x, const int* __restrict__ u,
                                 float* __restrict__ out, int first) {
    int i = blockIdx.x;
    int lane = threadIdx.x;
    float v = 0.25f * x[(size_t)u[i] * 64 + lane];
    if (first) out[(size_t)i * 64 + lane] = v;
    else       out[(size_t)i * 64 + lane] += v;
}

// Fallback if workspace is too small for CSR: edge-parallel atomic scatter.
__global__ void spmv_atomic_kernel(const float* __restrict__ x, float* y,
                                   const int* __restrict__ src, const int* __restrict__ dst,
                                   const float* __restrict__ val, int n_edges) {
    int lane = threadIdx.x & 63;
    int e = blockIdx.x * (blockDim.x >> 6) + (threadIdx.x >> 6);
    if (e >= n_edges) return;
    float v = val[e];
    atomicAdd(&y[(size_t)dst[e] * 64 + lane], v * x[(size_t)src[e] * 64 + lane]);
}

extern "C" void kernel_launch(void* const* d_in, const int* in_sizes, int n_in,
                              void* d_out, int out_size, void* d_ws, size_t ws_size,
                              hipStream_t stream) {
    const float* user_emb = (const float*)d_in[0];
    const float* item_emb = (const float*)d_in[1];
    const int*   edge_src = (const int*)d_in[2];
    const int*   edge_dst = (const int*)d_in[3];
    const float* edge_val = (const float*)d_in[4];
    const int*   u        = (const int*)d_in[5];
    float* out = (float*)d_out;

    const int n_users = in_sizes[0] / 64;
    const int n_items = in_sizes[1] / 64;
    const int n_nodes = n_users + n_items;
    const int n_edges = in_sizes[2];
    const int n_u     = in_sizes[5];

    const size_t xbytes = (size_t)n_nodes * 64 * sizeof(float);
    char* w = (char*)d_ws;
    float* x_a = (float*)w; w += xbytes;
    float* x_b = (float*)w; w += xbytes;

    // concat -> x_a
    long n_user4 = (long)n_users * 16;
    long total4  = (long)n_nodes * 16;
    concat_kernel<<<2048, 256, 0, stream>>>((const float4*)user_emb, (const float4*)item_emb,
                                            (float4*)x_a, n_user4, total4);

    const size_t csr_need = 2 * xbytes + (size_t)n_edges * 8
                          + ((size_t)n_nodes + 1) * 4 + (size_t)n_nodes * 4 + 8192;
    const bool use_csr = (ws_size >= csr_need);

    float* cur = x_a;
    float* nxt = x_b;

    out_accum_kernel<<<n_u, 64, 0, stream>>>(cur, u, out, 1);

    if (use_csr) {
        int2* csr      = (int2*)w;  w += (size_t)n_edges * 8;
        int*  row_ptr  = (int*)w;   w += ((size_t)n_nodes + 1) * 4;
        int*  cursor   = (int*)w;   w += (size_t)n_nodes * 4;
        int*  blk_sums = (int*)w;

        hipMemsetAsync(cursor, 0, (size_t)n_nodes * 4, stream);
        hist_kernel<<<2048, 256, 0, stream>>>(edge_dst, cursor, n_edges);
        int nblk = (n_nodes + SCAN_BS - 1) / SCAN_BS;   // 586 for this shape (<=1024)
        scan_blocks_kernel<<<nblk, SCAN_BS, 0, stream>>>(cursor, row_ptr, blk_sums, n_nodes);
        scan_sums_kernel<<<1, 1024, 0, stream>>>(blk_sums, nblk);
        scan_finalize_kernel<<<nblk, SCAN_BS, 0, stream>>>(row_ptr, blk_sums, cursor,
                                                           n_nodes, n_edges);
        scatter_kernel<<<2048, 256, 0, stream>>>(edge_src, edge_dst, edge_val, cursor,
                                                 csr, n_edges);

        for (int l = 0; l < 3; ++l) {
            spmv_kernel<<<(n_nodes + 3) / 4, 256, 0, stream>>>(cur, nxt, row_ptr,
                                                               csr, n_nodes);
            out_accum_kernel<<<n_u, 64, 0, stream>>>(nxt, u, out, 0);
            float* t = cur; cur = nxt; nxt = t;
        }
    } else {
        for (int l = 0; l < 3; ++l) {
            hipMemsetAsync(nxt, 0, xbytes, stream);
            spmv_atomic_kernel<<<(n_edges + 3) / 4, 256, 0, stream>>>(cur, nxt, edge_src,
                                                                      edge_dst, edge_val, n_edges);
            out_accum_kernel<<<n_u, 64, 0, stream>>>(nxt, u, out, 0);
            float* t = cur; cur = nxt; nxt = t;
        }
    }
}